// Round 2
// baseline (531.284 us; speedup 1.0000x reference)
//
#include <hip/hip_runtime.h>

// Shapes from the reference:
//   action [B=128, A=256] f32, conv_w [E=256, A=256] f32, conv_b [E=256] f32
//   out [B=128, E=256, H=64, W=64] f32  (512 MiB -> store-BW bound, ~85us floor)
#define B_DIM 128
#define A_DIM 256
#define E_DIM 256
#define HW    4096   // 64*64

typedef float f32x4 __attribute__((ext_vector_type(4)));

// Kernel 1: y[b,e] = relu(dot(action[b,:], conv_w[e,:]) + conv_b[e])
// One block per b (128 blocks), one thread per e (256 threads). ~2us total.
__global__ void __launch_bounds__(256) compute_y_kernel(
    const float* __restrict__ action,
    const float* __restrict__ conv_w,
    const float* __restrict__ conv_b,
    float* __restrict__ y)
{
    const int b = blockIdx.x;
    const int e = threadIdx.x;

    __shared__ float act[A_DIM];
    act[e] = action[b * A_DIM + e];   // blockDim.x == A_DIM == 256
    __syncthreads();

    const float4* w4 = reinterpret_cast<const float4*>(conv_w + e * A_DIM);
    const float4* a4 = reinterpret_cast<const float4*>(act);

    float sum = conv_b[e];
    #pragma unroll
    for (int i = 0; i < A_DIM / 4; ++i) {
        float4 w = w4[i];
        float4 a = a4[i];
        sum = fmaf(a.x, w.x, sum);
        sum = fmaf(a.y, w.y, sum);
        sum = fmaf(a.z, w.z, sum);
        sum = fmaf(a.w, w.w, sum);
    }
    y[b * E_DIM + e] = fmaxf(sum, 0.0f);
}

// Kernel 2: broadcast, restructured to match the 6.28 TB/s fillBuffer shape.
//   - 2048 blocks x 256 threads (8 blocks/CU -> 32 waves/CU, max occupancy)
//   - each block owns a CONTIGUOUS 256 KB span of out = 16 (b,e)-chunks
//   - 16 thread-uniform y loads (scalar-load'able, hoisted by full unroll)
//   - 64 regular dwordx4 stores per thread, each wave writing 1 KB contiguous
//     (full 64B lines -> no read-for-ownership fetch)
// vs previous version: 16x fatter blocks (32768 -> 2048), NT stores dropped
// (the rocclr fill kernel proves REGULAR stores hit 6.28 TB/s on this chip).
__global__ void __launch_bounds__(256) broadcast_y_kernel(
    const float* __restrict__ y,
    f32x4* __restrict__ out)
{
    const int t = threadIdx.x;
    // 16384 f32x4 per block; 1024 f32x4 per (b,e) chunk; 16 chunks per block.
    f32x4* dst = out + (size_t)blockIdx.x * 16384 + t;
    const int ybase = blockIdx.x * 16;

    #pragma unroll
    for (int k = 0; k < 16; ++k) {
        const float v = y[ybase + k];          // uniform across the block
        const f32x4 v4 = {v, v, v, v};
        #pragma unroll
        for (int j = 0; j < 4; ++j) {
            dst[k * 1024 + j * 256] = v4;      // regular streaming store
        }
    }
}

extern "C" void kernel_launch(void* const* d_in, const int* in_sizes, int n_in,
                              void* d_out, int out_size, void* d_ws, size_t ws_size,
                              hipStream_t stream) {
    const float* action = (const float*)d_in[0];
    const float* conv_w = (const float*)d_in[1];
    const float* conv_b = (const float*)d_in[2];
    float* out = (float*)d_out;
    float* y   = (float*)d_ws;   // needs B*E*4 = 128 KiB scratch

    compute_y_kernel<<<B_DIM, 256, 0, stream>>>(action, conv_w, conv_b, y);

    // (B*E*HW/4) f32x4 / 16384 per block = 2048 blocks
    broadcast_y_kernel<<<2048, 256, 0, stream>>>(
        y, reinterpret_cast<f32x4*>(out));
}

// Round 3
// 521.095 us; speedup vs baseline: 1.0196x; 1.0196x over previous
//
#include <hip/hip_runtime.h>

// out[b,e,h,w] = relu(dot(action[b,:], conv_w[e,:]) + conv_b[e]) broadcast over HxW.
//   action [128,256] f32, conv_w [256,256] f32, conv_b [256] f32
//   out [128,256,64,64] f32 = 512 MiB  -> pure store-BW bound, ~82-85us floor.
// Single fused kernel, shaped like the 6.28 TB/s rocclr fill kernel:
//   2048 blocks x 256 threads (8 blocks/CU), each block owns a contiguous
//   256 KB output span (16 (b,e)-chunks, all same b). Prologue computes the
//   16 y-values with 16-lane-group dot products + shuffle reduce (~1us),
//   then 64 fully-unrolled regular dwordx4 stores per thread.
#define B_DIM 128
#define A_DIM 256
#define E_DIM 256
#define HW    4096   // 64*64
#define CHUNKS_PER_BLOCK 16
#define NBLOCKS (B_DIM * E_DIM / CHUNKS_PER_BLOCK)   // 2048

typedef float f32x4 __attribute__((ext_vector_type(4)));

__global__ void __launch_bounds__(256) fused_embed_kernel(
    const float* __restrict__ action,
    const float* __restrict__ conv_w,
    const float* __restrict__ conv_b,
    f32x4* __restrict__ out)
{
    const int t = threadIdx.x;
    const int ybase = blockIdx.x * CHUNKS_PER_BLOCK;  // 16 consecutive (b,e)
    const int g = t >> 4;          // which chunk this thread's group computes
    const int l = t & 15;          // lane within the 16-thread group
    const int be = ybase + g;
    const int b  = be >> 8;        // E_DIM == 256; all 16 chunks share b
    const int e  = be & 255;

    // Each lane covers 16 consecutive a-elements of the length-256 dot.
    const float4* a4 = reinterpret_cast<const float4*>(action + b * A_DIM + l * 16);
    const float4* w4 = reinterpret_cast<const float4*>(conv_w + e * A_DIM + l * 16);
    float s = 0.0f;
    #pragma unroll
    for (int i = 0; i < 4; ++i) {
        float4 a = a4[i];
        float4 w = w4[i];
        s = fmaf(a.x, w.x, s);
        s = fmaf(a.y, w.y, s);
        s = fmaf(a.z, w.z, s);
        s = fmaf(a.w, w.w, s);
    }
    // Reduce across the 16-lane group (groups are contiguous within a wave64).
    s += __shfl_xor(s, 8, 16);
    s += __shfl_xor(s, 4, 16);
    s += __shfl_xor(s, 2, 16);
    s += __shfl_xor(s, 1, 16);

    __shared__ float ysm[CHUNKS_PER_BLOCK];
    if (l == 0) ysm[g] = fmaxf(s + conv_b[e], 0.0f);
    __syncthreads();

    // Broadcast-read the 16 y values (same-address LDS reads: free broadcast).
    float yv[CHUNKS_PER_BLOCK];
    #pragma unroll
    for (int k = 0; k < CHUNKS_PER_BLOCK; ++k) yv[k] = ysm[k];

    // Pure store stream: 64 dwordx4 per thread; each wave instruction writes
    // 1 KB contiguous; block covers a contiguous 256 KB span of out.
    f32x4* dst = out + (size_t)blockIdx.x * (CHUNKS_PER_BLOCK * HW / 4) + t;
    #pragma unroll
    for (int k = 0; k < CHUNKS_PER_BLOCK; ++k) {
        const f32x4 v4 = {yv[k], yv[k], yv[k], yv[k]};
        #pragma unroll
        for (int j = 0; j < 4; ++j) {
            dst[k * (HW / 4) + j * 256] = v4;
        }
    }
}

extern "C" void kernel_launch(void* const* d_in, const int* in_sizes, int n_in,
                              void* d_out, int out_size, void* d_ws, size_t ws_size,
                              hipStream_t stream) {
    const float* action = (const float*)d_in[0];
    const float* conv_w = (const float*)d_in[1];
    const float* conv_b = (const float*)d_in[2];

    fused_embed_kernel<<<NBLOCKS, 256, 0, stream>>>(
        action, conv_w, conv_b, reinterpret_cast<f32x4*>(d_out));
}